// Round 3
// baseline (227.417 us; speedup 1.0000x reference)
//
#include <hip/hip_runtime.h>
#include <hip/hip_bf16.h>

#define HS 64
#define NH 16
#define NG 16
#define TT 2048
#define CC 1024
#define BBATCH 4
#define TG 128
#define SS 129   // TG+1

typedef __attribute__((ext_vector_type(8))) short bf16x8;
typedef __attribute__((ext_vector_type(4))) float f32x4;

__device__ __forceinline__ float bf2f(ushort u) {
  return __uint_as_float(((unsigned)u) << 16);
}
__device__ __forceinline__ ushort f2bf(float f) {
  unsigned x = __float_as_uint(f);
  x += 0x7fff + ((x >> 16) & 1);
  return (ushort)(x >> 16);
}
__device__ __forceinline__ bf16x8 mk8(ushort4 a0, ushort4 a1) {
  bf16x8 v;
  v[0] = (short)a0.x; v[1] = (short)a0.y; v[2] = (short)a0.z; v[3] = (short)a0.w;
  v[4] = (short)a1.x; v[5] = (short)a1.y; v[6] = (short)a1.z; v[7] = (short)a1.w;
  return v;
}
__device__ __forceinline__ void load_lds16(const ushort* g, ushort* l) {
  __builtin_amdgcn_global_load_lds((const __attribute__((address_space(1))) unsigned int*)g,
                                   (__attribute__((address_space(3))) unsigned int*)l, 16, 0, 0);
}

// ---------------- fp32 -> bf16 convert ----------------
__global__ void cvt_f32_bf16(const float* __restrict__ src, ushort* __restrict__ dst, int n4) {
  int stride = gridDim.x * blockDim.x;
  for (int i = blockIdx.x * blockDim.x + threadIdx.x; i < n4; i += stride) {
    float4 v = ((const float4*)src)[i];
    ushort4 o;
    o.x = f2bf(v.x); o.y = f2bf(v.y); o.z = f2bf(v.z); o.w = f2bf(v.w);
    ((ushort4*)dst)[i] = o;
  }
}

// ---------------- GEMM mainloop core (128x128 tile, BK=64, global_load_lds) ----------------
// Both A/B frag reads use the same contiguous-k slot permutation -> cancels in MFMA.
#define GEMM_CORE(A_, B_, K_, m0_, n0_)                                            \
  {                                                                                \
    const int rA = tid >> 3, cA = (tid & 7) * 8;                                   \
    for (int k0 = 0; k0 < (K_); k0 += 64) {                                        \
      _Pragma("unroll")                                                            \
      for (int it = 0; it < 4; ++it) {                                             \
        load_lds16((A_) + (size_t)((m0_) + it * 32 + rA) * (K_) + k0 + cA,         \
                   As + it * 2048 + wv * 512);                                     \
        load_lds16((B_) + (size_t)((n0_) + it * 32 + rA) * (K_) + k0 + cA,         \
                   Bs + it * 2048 + wv * 512);                                     \
      }                                                                            \
      __syncthreads();                                                             \
      _Pragma("unroll")                                                            \
      for (int kk = 0; kk < 64; kk += 32) {                                        \
        bf16x8 af[4], bfr[4];                                                      \
        _Pragma("unroll")                                                          \
        for (int i = 0; i < 4; ++i)                                                \
          af[i] = *(const bf16x8*)(As + (wr * 64 + i * 16 + lo) * 64 + kk + 8 * hi); \
        _Pragma("unroll")                                                          \
        for (int j = 0; j < 4; ++j)                                                \
          bfr[j] = *(const bf16x8*)(Bs + (wc * 64 + j * 16 + lo) * 64 + kk + 8 * hi); \
        _Pragma("unroll")                                                          \
        for (int i = 0; i < 4; ++i)                                                \
          _Pragma("unroll")                                                        \
          for (int j = 0; j < 4; ++j)                                              \
            acc[i][j] = __builtin_amdgcn_mfma_f32_16x16x32_bf16(af[i], bfr[j], acc[i][j], 0, 0, 0); \
      }                                                                            \
      __syncthreads();                                                             \
    }                                                                              \
  }

// ---------------- plain bf16 GEMM:  C[m][n] = sum_k A[m][k] * Bw[n][k] ----------------
template <bool OUT_BF16>
__global__ __launch_bounds__(256) void gemm_bt(const ushort* __restrict__ A,
                                               const ushort* __restrict__ Bw,
                                               void* __restrict__ Cout,
                                               int M, int N, int K) {
  __shared__ ushort As[128 * 64];
  __shared__ ushort Bs[128 * 64];
  const int m0 = blockIdx.y * 128;
  const int n0 = blockIdx.x * 128;
  const int tid = threadIdx.x;
  const int lane = tid & 63;
  const int wv = tid >> 6;
  const int wr = wv >> 1, wc = wv & 1;
  const int lo = lane & 15, hi = lane >> 4;

  f32x4 acc[4][4];
#pragma unroll
  for (int i = 0; i < 4; ++i)
#pragma unroll
    for (int j = 0; j < 4; ++j) acc[i][j] = (f32x4)0.0f;

  GEMM_CORE(A, Bw, K, m0, n0)

#pragma unroll
  for (int i = 0; i < 4; ++i) {
    int row = m0 + wr * 64 + i * 16 + 4 * hi;
#pragma unroll
    for (int j = 0; j < 4; ++j) {
      int col = n0 + wc * 64 + j * 16 + lo;
#pragma unroll
      for (int r = 0; r < 4; ++r) {
        float v = acc[i][j][r];
        if constexpr (OUT_BF16) {
          ((ushort*)Cout)[(size_t)(row + r) * N + col] = f2bf(v);
        } else {
          ((float*)Cout)[(size_t)(row + r) * N + col] = v;
        }
      }
    }
  }
}

// ---------------- qkv GEMM with fused RoPE + regroup + per-group mean ----------------
// Tile 128 rows = one (b, g) group; 128 cols = 2 heads of one of {q,k,v}.
__global__ __launch_bounds__(256) void gemm_qkv_rope(const ushort* __restrict__ A,
                                                     const ushort* __restrict__ Bw,
                                                     const float* __restrict__ fc,
                                                     const float* __restrict__ fs,
                                                     ushort* __restrict__ qg,
                                                     ushort* __restrict__ kg,
                                                     ushort* __restrict__ vg,
                                                     float* __restrict__ yq,
                                                     float* __restrict__ yk) {
  __shared__ ushort As[128 * 64];
  __shared__ ushort Bs[128 * 64];
  __shared__ float colsum[2][128];
  const int K = CC, m0 = blockIdx.y * 128, n0 = blockIdx.x * 128;
  const int tid = threadIdx.x;
  const int lane = tid & 63;
  const int wv = tid >> 6;
  const int wr = wv >> 1, wc = wv & 1;
  const int lo = lane & 15, hi = lane >> 4;

  f32x4 acc[4][4];
#pragma unroll
  for (int i = 0; i < 4; ++i)
#pragma unroll
    for (int j = 0; j < 4; ++j) acc[i][j] = (f32x4)0.0f;

  GEMM_CORE(A, Bw, K, m0, n0)

  const int b = m0 >> 11;          // m0 / 2048
  const int tseq0 = m0 & 2047;     // g*128
  const int g = tseq0 >> 7;
  const int part = n0 >> 10;       // 0=q 1=k 2=v
  const int cbase = n0 & 1023;
  ushort* G = part == 0 ? qg : (part == 1 ? kg : vg);

  float msum[4] = {0.f, 0.f, 0.f, 0.f};
#pragma unroll
  for (int j = 0; j < 4; ++j) {
    const int col = wc * 64 + j * 16 + lo;
    const int d = (cbase + col) & 63;
    const int h = (cbase + col) >> 6;
    const int blk = (b * 16 + h) * 16 + g;
    ushort* dst = G + ((size_t)blk * SS) * 64 + d;
#pragma unroll
    for (int i = 0; i < 4; ++i) {
#pragma unroll
      for (int r = 0; r < 4; ++r) {
        const int row = wr * 64 + i * 16 + 4 * hi + r;
        float v = acc[i][j][r];
        float o;
        if (part < 2) {
          float p = __shfl_xor(v, 1);
          const int ts = tseq0 + row;
          float cc2 = fc[ts * 32 + (d >> 1)];
          float sn2 = fs[ts * 32 + (d >> 1)];
          o = (d & 1) ? (p * sn2 + v * cc2) : (v * cc2 - p * sn2);
        } else {
          o = v;
        }
        msum[j] += o;
        dst[(size_t)row * 64] = f2bf(o);
      }
    }
  }
#pragma unroll
  for (int j = 0; j < 4; ++j) {
    msum[j] += __shfl_xor(msum[j], 16);
    msum[j] += __shfl_xor(msum[j], 32);
  }
  if (hi == 0) {
#pragma unroll
    for (int j = 0; j < 4; ++j) colsum[wr][wc * 64 + j * 16 + lo] = msum[j];
  }
  __syncthreads();
  if (wr == 0 && hi == 0) {
#pragma unroll
    for (int j = 0; j < 4; ++j) {
      const int col = wc * 64 + j * 16 + lo;
      const float mean = (colsum[0][col] + colsum[1][col]) * (1.0f / 128.0f);
      const int d = (cbase + col) & 63;
      const int h = (cbase + col) >> 6;
      const int blk = (b * 16 + h) * 16 + g;
      G[((size_t)blk * SS + 128) * 64 + d] = f2bf(mean);
      if (g < 15 && part < 2) {
        float* Y = (part == 0) ? yq : yk;
        Y[((size_t)(b * 16 + h) * 15 + g) * 64 + d] = mean;
      }
    }
  }
}

// ---------------- causal attention per (b,h,g), S=129, d=64 — MFMA version ----------------
__global__ __launch_bounds__(256) void attn1(const ushort* __restrict__ qg,
                                             const ushort* __restrict__ kg,
                                             const ushort* __restrict__ vg,
                                             ushort* __restrict__ xo, float* __restrict__ attm) {
  __shared__ ushort qs[144][68];
  __shared__ ushort ks[144][68];
  __shared__ ushort vt[64][148];   // V^T: vt[d][key]
  __shared__ ushort obuf[4][16][68];
  const int blk = blockIdx.x;
  const int g = blk & 15, h = (blk >> 4) & 15, b = blk >> 8;
  const int tid = threadIdx.x;
  const int lane = tid & 63, wv = tid >> 6;
  const int lo = lane & 15, hi = lane >> 4;
  const size_t gbase = (size_t)blk * SS * HS;

  {
    ushort* vflat = &vt[0][0];
    for (int idx = tid; idx < 64 * 148 / 4; idx += 256)
      *(ushort4*)(vflat + idx * 4) = make_ushort4(0, 0, 0, 0);
  }
  __syncthreads();
  for (int idx = tid; idx < 144 * 16; idx += 256) {
    int s = idx >> 4, c = (idx & 15) * 4;
    if (s < SS) {
      *(ushort4*)&qs[s][c] = *(const ushort4*)(qg + gbase + s * HS + c);
      *(ushort4*)&ks[s][c] = *(const ushort4*)(kg + gbase + s * HS + c);
      ushort4 v4 = *(const ushort4*)(vg + gbase + s * HS + c);
      vt[c][s] = v4.x; vt[c + 1][s] = v4.y; vt[c + 2][s] = v4.z; vt[c + 3][s] = v4.w;
    } else {
      *(ushort4*)&qs[s][c] = make_ushort4(0, 0, 0, 0);
      *(ushort4*)&ks[s][c] = make_ushort4(0, 0, 0, 0);
    }
  }
  __syncthreads();

#pragma unroll
  for (int ti = 0; ti < 3; ++ti) {
    const int t = (ti == 0) ? (8 - wv)
                : (ti == 1) ? ((wv == 3) ? 4 : (wv + 1))
                            : ((wv == 3) ? 0 : -1);
    if (t < 0) continue;
    const int q0 = t * 16;

    bf16x8 bq[2];
#pragma unroll
    for (int k2 = 0; k2 < 2; ++k2)
      bq[k2] = mk8(*(const ushort4*)&qs[q0 + lo][k2 * 32 + 4 * hi],
                   *(const ushort4*)&qs[q0 + lo][k2 * 32 + 16 + 4 * hi]);

    f32x4 sc[9];
#pragma unroll
    for (int n = 0; n < 9; ++n) sc[n] = (f32x4)0.0f;
#pragma unroll
    for (int n = 0; n < 9; ++n) {
      if (n > t) continue;
#pragma unroll
      for (int k2 = 0; k2 < 2; ++k2) {
        bf16x8 ak = mk8(*(const ushort4*)&ks[n * 16 + lo][k2 * 32 + 4 * hi],
                        *(const ushort4*)&ks[n * 16 + lo][k2 * 32 + 16 + 4 * hi]);
        sc[n] = __builtin_amdgcn_mfma_f32_16x16x32_bf16(ak, bq[k2], sc[n], 0, 0, 0);
      }
    }

    const int qi = q0 + lo;
    float mx = -INFINITY;
#pragma unroll
    for (int n = 0; n < 9; ++n) {
      if (n > t) continue;
#pragma unroll
      for (int r = 0; r < 4; ++r) {
        int kj = n * 16 + 4 * hi + r;
        float v = (kj <= qi) ? sc[n][r] * 0.125f : -INFINITY;
        sc[n][r] = v;
        mx = fmaxf(mx, v);
      }
    }
    mx = fmaxf(mx, __shfl_xor(mx, 16));
    mx = fmaxf(mx, __shfl_xor(mx, 32));
    float sum = 0.f;
#pragma unroll
    for (int n = 0; n < 9; ++n) {
      if (n > t) continue;
#pragma unroll
      for (int r = 0; r < 4; ++r) {
        float e = __expf(sc[n][r] - mx);
        sc[n][r] = e;
        sum += e;
      }
    }
    sum += __shfl_xor(sum, 16);
    sum += __shfl_xor(sum, 32);
    const float inv = 1.0f / sum;

    f32x4 oac[4];
#pragma unroll
    for (int m = 0; m < 4; ++m) oac[m] = (f32x4)0.0f;
#pragma unroll
    for (int s2 = 0; s2 < 5; ++s2) {
      if (s2 > (t >> 1)) continue;
      const int kt1ok = (2 * s2 + 1 <= t);
      bf16x8 pb;
#pragma unroll
      for (int e = 0; e < 4; ++e) pb[e] = (short)f2bf(sc[2 * s2][e] * inv);
      if (kt1ok) {
#pragma unroll
        for (int e = 0; e < 4; ++e) pb[e + 4] = (short)f2bf(sc[2 * s2 + 1][e] * inv);
      } else {
#pragma unroll
        for (int e = 0; e < 4; ++e) pb[e + 4] = 0;
      }
#pragma unroll
      for (int m = 0; m < 4; ++m) {
        ushort4 a0 = *(const ushort4*)&vt[m * 16 + lo][32 * s2 + 4 * hi];
        ushort4 a1 = kt1ok ? *(const ushort4*)&vt[m * 16 + lo][32 * s2 + 16 + 4 * hi]
                           : make_ushort4(0, 0, 0, 0);
        oac[m] = __builtin_amdgcn_mfma_f32_16x16x32_bf16(mk8(a0, a1), pb, oac[m], 0, 0, 0);
      }
    }

    if (t < 8) {
#pragma unroll
      for (int m = 0; m < 4; ++m)
#pragma unroll
        for (int r = 0; r < 4; ++r)
          obuf[wv][lo][m * 16 + 4 * hi + r] = f2bf(oac[m][r]);
#pragma unroll
      for (int it = 0; it < 4; ++it) {
        int idx = lane + 64 * it;
        int r = idx >> 4;
        int c4 = (idx & 15) * 4;
        uint2 val = *(const uint2*)&obuf[wv][r][c4];
        int tok = g * TG + t * 16 + r;
        *(uint2*)(xo + ((size_t)(b * TT + tok)) * CC + h * HS + c4) = val;
      }
    } else {
      if (lo == 0) {
#pragma unroll
        for (int m = 0; m < 4; ++m)
#pragma unroll
          for (int r = 0; r < 4; ++r)
            attm[(size_t)blk * 64 + m * 16 + 4 * hi + r] = oac[m][r];
      }
    }
  }
}

// ---------------- second (tiny) causal attention over 15 group-mean tokens ----------------
__global__ __launch_bounds__(64) void attn2(const float* __restrict__ yq,
                                            const float* __restrict__ yk,
                                            const float* __restrict__ attm,
                                            float* __restrict__ yv) {
  __shared__ float qs2[15][64], ks2[15][64], avs[15][64], srow[16];
  int bh = blockIdx.x, lane = threadIdx.x;
  for (int j = 0; j < 15; ++j) {
    qs2[j][lane] = yq[((size_t)bh * 15 + j) * 64 + lane];
    ks2[j][lane] = yk[((size_t)bh * 15 + j) * 64 + lane];
    avs[j][lane] = attm[((size_t)bh * 16 + j) * 64 + lane];
  }
  __syncthreads();
  for (int i = 0; i < 15; ++i) {
    float qv = qs2[i][lane];
    for (int j = 0; j <= i; ++j) {
      float t = qv * ks2[j][lane];
#pragma unroll
      for (int off = 32; off > 0; off >>= 1) t += __shfl_xor(t, off);
      if (lane == 0) srow[j] = t * 0.125f;
    }
    __syncthreads();
    float mx = -INFINITY;
    for (int j = 0; j <= i; ++j) mx = fmaxf(mx, srow[j]);
    float den = 0;
    for (int j = 0; j <= i; ++j) den += __expf(srow[j] - mx);
    float inv = 1.0f / den;
    float o = 0;
    for (int j = 0; j <= i; ++j) o += __expf(srow[j] - mx) * inv * avs[j][lane];
    yv[((size_t)bh * 15 + i) * 64 + lane] = o;
    __syncthreads();
  }
}

extern "C" void kernel_launch(void* const* d_in, const int* in_sizes, int n_in,
                              void* d_out, int out_size, void* d_ws, size_t ws_size,
                              hipStream_t stream) {
  const float* x      = (const float*)d_in[0];
  const float* w_attn = (const float*)d_in[1];
  const float* w_proj = (const float*)d_in[2];
  const float* fc     = (const float*)d_in[3];
  const float* fs     = (const float*)d_in[4];
  float* out = (float*)d_out;

  char* ws = (char*)d_ws;
  ushort* xb   = (ushort*)(ws);               // x bf16; dead after qkv gemm
  ushort* xo   = (ushort*)(ws);               // reuse xb region (attn1 output)
  ushort* wab  = (ushort*)(ws + 16777216);    // dead after qkv gemm
  float*  attm = (float*) (ws + 16777216);    // reuse wab region
  ushort* wpb  = (ushort*)(ws + 23068672);
  ushort* qg   = (ushort*)(ws + 25165824);    // (B,H,G,129,64) bf16
  ushort* kg   = (ushort*)(ws + 42074112);
  ushort* vg   = (ushort*)(ws + 58982400);    // end 75,890,688

  float* yq = out + 8388608;
  float* yk = out + 8450048;
  float* yv = out + 8511488;

  cvt_f32_bf16<<<2048, 256, 0, stream>>>(x, xb, 8388608 / 4);
  cvt_f32_bf16<<<1024, 256, 0, stream>>>(w_attn, wab, 3145728 / 4);
  cvt_f32_bf16<<<512, 256, 0, stream>>>(w_proj, wpb, 1048576 / 4);
  gemm_qkv_rope<<<dim3(24, 64), 256, 0, stream>>>(xb, wab, fc, fs, qg, kg, vg, yq, yk);
  attn1<<<1024, 256, 0, stream>>>(qg, kg, vg, xo, attm);
  attn2<<<64, 64, 0, stream>>>(yq, yk, attm, yv);
  gemm_bt<false><<<dim3(8, 64), 256, 0, stream>>>(xo, wpb, out, 8192, 1024, 1024);
}

// Round 5
// 224.387 us; speedup vs baseline: 1.0135x; 1.0135x over previous
//
#include <hip/hip_runtime.h>
#include <hip/hip_bf16.h>

#define HS 64
#define NH 16
#define NG 16
#define TT 2048
#define CC 1024
#define BBATCH 4
#define TG 128
#define SS 129   // TG+1

typedef __attribute__((ext_vector_type(8))) short bf16x8;
typedef __attribute__((ext_vector_type(4))) float f32x4;

__device__ __forceinline__ float bf2f(ushort u) {
  return __uint_as_float(((unsigned)u) << 16);
}
__device__ __forceinline__ ushort f2bf(float f) {
  unsigned x = __float_as_uint(f);
  x += 0x7fff + ((x >> 16) & 1);
  return (ushort)(x >> 16);
}
__device__ __forceinline__ bf16x8 mk8(ushort4 a0, ushort4 a1) {
  bf16x8 v;
  v[0] = (short)a0.x; v[1] = (short)a0.y; v[2] = (short)a0.z; v[3] = (short)a0.w;
  v[4] = (short)a1.x; v[5] = (short)a1.y; v[6] = (short)a1.z; v[7] = (short)a1.w;
  return v;
}
__device__ __forceinline__ void load_lds16(const ushort* g, ushort* l) {
  __builtin_amdgcn_global_load_lds((const __attribute__((address_space(1))) unsigned int*)g,
                                   (__attribute__((address_space(3))) unsigned int*)l, 16, 0, 0);
}

// ---------------- fp32 -> bf16 convert ----------------
__global__ void cvt_f32_bf16(const float* __restrict__ src, ushort* __restrict__ dst, int n4) {
  int stride = gridDim.x * blockDim.x;
  for (int i = blockIdx.x * blockDim.x + threadIdx.x; i < n4; i += stride) {
    float4 v = ((const float4*)src)[i];
    ushort4 o;
    o.x = f2bf(v.x); o.y = f2bf(v.y); o.z = f2bf(v.z); o.w = f2bf(v.w);
    ((ushort4*)dst)[i] = o;
  }
}

// ---------------- GEMM mainloop core (128x128 tile, BK=64, global_load_lds) ----------------
// Both A/B frag reads use the same contiguous-k slot permutation -> cancels in MFMA.
#define GEMM_CORE(A_, B_, K_, m0_, n0_)                                            \
  {                                                                                \
    const int rA = tid >> 3, cA = (tid & 7) * 8;                                   \
    for (int k0 = 0; k0 < (K_); k0 += 64) {                                        \
      _Pragma("unroll")                                                            \
      for (int it = 0; it < 4; ++it) {                                             \
        load_lds16((A_) + (size_t)((m0_) + it * 32 + rA) * (K_) + k0 + cA,         \
                   As + it * 2048 + wv * 512);                                     \
        load_lds16((B_) + (size_t)((n0_) + it * 32 + rA) * (K_) + k0 + cA,         \
                   Bs + it * 2048 + wv * 512);                                     \
      }                                                                            \
      __syncthreads();                                                             \
      _Pragma("unroll")                                                            \
      for (int kk = 0; kk < 64; kk += 32) {                                        \
        bf16x8 af[4], bfr[4];                                                      \
        _Pragma("unroll")                                                          \
        for (int i = 0; i < 4; ++i)                                                \
          af[i] = *(const bf16x8*)(As + (wr * 64 + i * 16 + lo) * 64 + kk + 8 * hi); \
        _Pragma("unroll")                                                          \
        for (int j = 0; j < 4; ++j)                                                \
          bfr[j] = *(const bf16x8*)(Bs + (wc * 64 + j * 16 + lo) * 64 + kk + 8 * hi); \
        _Pragma("unroll")                                                          \
        for (int i = 0; i < 4; ++i)                                                \
          _Pragma("unroll")                                                        \
          for (int j = 0; j < 4; ++j)                                              \
            acc[i][j] = __builtin_amdgcn_mfma_f32_16x16x32_bf16(af[i], bfr[j], acc[i][j], 0, 0, 0); \
      }                                                                            \
      __syncthreads();                                                             \
    }                                                                              \
  }

// ---------------- plain bf16 GEMM:  C[m][n] = sum_k A[m][k] * Bw[n][k] ----------------
template <bool OUT_BF16>
__global__ __launch_bounds__(256) void gemm_bt(const ushort* __restrict__ A,
                                               const ushort* __restrict__ Bw,
                                               void* __restrict__ Cout,
                                               int M, int N, int K) {
  __shared__ ushort As[128 * 64];
  __shared__ ushort Bs[128 * 64];
  const int m0 = blockIdx.y * 128;
  const int n0 = blockIdx.x * 128;
  const int tid = threadIdx.x;
  const int lane = tid & 63;
  const int wv = tid >> 6;
  const int wr = wv >> 1, wc = wv & 1;
  const int lo = lane & 15, hi = lane >> 4;

  f32x4 acc[4][4];
#pragma unroll
  for (int i = 0; i < 4; ++i)
#pragma unroll
    for (int j = 0; j < 4; ++j) acc[i][j] = (f32x4)0.0f;

  GEMM_CORE(A, Bw, K, m0, n0)

#pragma unroll
  for (int i = 0; i < 4; ++i) {
    int row = m0 + wr * 64 + i * 16 + 4 * hi;
#pragma unroll
    for (int j = 0; j < 4; ++j) {
      int col = n0 + wc * 64 + j * 16 + lo;
#pragma unroll
      for (int r = 0; r < 4; ++r) {
        float v = acc[i][j][r];
        if constexpr (OUT_BF16) {
          ((ushort*)Cout)[(size_t)(row + r) * N + col] = f2bf(v);
        } else {
          ((float*)Cout)[(size_t)(row + r) * N + col] = v;
        }
      }
    }
  }
}

// ---------------- qkv GEMM with fused RoPE + regroup + per-group mean ----------------
// Tile 128 rows = one (b, g) group; 128 cols = 2 heads of one of {q,k,v}.
// Epilogue bounces the post-RoPE tile through LDS for coalesced uint4 stores.
__global__ __launch_bounds__(256) void gemm_qkv_rope(const ushort* __restrict__ A,
                                                     const ushort* __restrict__ Bw,
                                                     const float* __restrict__ fc,
                                                     const float* __restrict__ fs,
                                                     ushort* __restrict__ qg,
                                                     ushort* __restrict__ kg,
                                                     ushort* __restrict__ vg,
                                                     float* __restrict__ yq,
                                                     float* __restrict__ yk) {
  __shared__ ushort smem[2 * 128 * 72];   // mainloop: As|Bs (32 KB); epilogue: epi[2][128][72]
  __shared__ float colsum[2][128];
  ushort* As = smem;
  ushort* Bs = smem + 128 * 64;
  typedef ushort epi_t[128][72];
  epi_t* epi = reinterpret_cast<epi_t*>(smem);

  const int K = CC, m0 = blockIdx.y * 128, n0 = blockIdx.x * 128;
  const int tid = threadIdx.x;
  const int lane = tid & 63;
  const int wv = tid >> 6;
  const int wr = wv >> 1, wc = wv & 1;
  const int lo = lane & 15, hi = lane >> 4;

  f32x4 acc[4][4];
#pragma unroll
  for (int i = 0; i < 4; ++i)
#pragma unroll
    for (int j = 0; j < 4; ++j) acc[i][j] = (f32x4)0.0f;

  GEMM_CORE(A, Bw, K, m0, n0)
  // last __syncthreads in GEMM_CORE: all waves done reading As/Bs -> safe to overwrite as epi

  const int b = m0 >> 11;          // m0 / 2048
  const int tseq0 = m0 & 2047;     // g*128
  const int g = tseq0 >> 7;
  const int part = n0 >> 10;       // 0=q 1=k 2=v
  const int cbase = n0 & 1023;
  const int h0 = cbase >> 6;       // first head of this tile
  ushort* G = part == 0 ? qg : (part == 1 ? kg : vg);

  float msum[4] = {0.f, 0.f, 0.f, 0.f};
#pragma unroll
  for (int j = 0; j < 4; ++j) {
    const int dcol = j * 16 + lo;  // d within head (head = h0 + wc)
#pragma unroll
    for (int i = 0; i < 4; ++i) {
#pragma unroll
      for (int r = 0; r < 4; ++r) {
        const int row = wr * 64 + i * 16 + 4 * hi + r;
        float v = acc[i][j][r];
        float o;
        if (part < 2) {
          float p = __shfl_xor(v, 1);
          const int ts = tseq0 + row;
          float cc2 = fc[ts * 32 + (dcol >> 1)];
          float sn2 = fs[ts * 32 + (dcol >> 1)];
          o = (dcol & 1) ? (p * sn2 + v * cc2) : (v * cc2 - p * sn2);
        } else {
          o = v;
        }
        msum[j] += o;
        epi[wc][row][dcol] = f2bf(o);
      }
    }
  }
#pragma unroll
  for (int j = 0; j < 4; ++j) {
    msum[j] += __shfl_xor(msum[j], 16);
    msum[j] += __shfl_xor(msum[j], 32);
  }
  if (hi == 0) {
#pragma unroll
    for (int j = 0; j < 4; ++j) colsum[wr][wc * 64 + j * 16 + lo] = msum[j];
  }
  __syncthreads();

  // coalesced writeout: 2 heads x 128 rows x 64 d, 16B per lane
#pragma unroll
  for (int it = 0; it < 8; ++it) {
    int idx = tid + 256 * it;      // 0..2047
    int hh = idx >> 10;
    int rem = idx & 1023;
    int r = rem >> 3;
    int c8 = (rem & 7) * 8;
    const int blk = (b * 16 + h0 + hh) * 16 + g;
    uint4 w = *(const uint4*)&epi[hh][r][c8];
    *(uint4*)(G + ((size_t)blk * SS + r) * 64 + c8) = w;
  }

  // mean token (+ y_q/y_k) from fp32 column sums
  if (wr == 0 && hi == 0) {
#pragma unroll
    for (int j = 0; j < 4; ++j) {
      const int col = wc * 64 + j * 16 + lo;
      const float mean = (colsum[0][col] + colsum[1][col]) * (1.0f / 128.0f);
      const int d = col & 63;
      const int h = h0 + (col >> 6);
      const int blk = (b * 16 + h) * 16 + g;
      G[((size_t)blk * SS + 128) * 64 + d] = f2bf(mean);
      if (g < 15 && part < 2) {
        float* Y = (part == 0) ? yq : yk;
        Y[((size_t)(b * 16 + h) * 15 + g) * 64 + d] = mean;
      }
    }
  }
}

// ---------------- causal attention per (b,h,g), S=129, d=64 — MFMA version ----------------
__global__ __launch_bounds__(256) void attn1(const ushort* __restrict__ qg,
                                             const ushort* __restrict__ kg,
                                             const ushort* __restrict__ vg,
                                             ushort* __restrict__ xo, float* __restrict__ attm) {
  __shared__ ushort qs[144][68];
  __shared__ ushort ks[144][68];
  __shared__ ushort vt[64][148];   // V^T: vt[d][key]
  __shared__ ushort obuf[4][16][68];
  const int blk = blockIdx.x;
  const int g = blk & 15, h = (blk >> 4) & 15, b = blk >> 8;
  const int tid = threadIdx.x;
  const int lane = tid & 63, wv = tid >> 6;
  const int lo = lane & 15, hi = lane >> 4;
  const size_t gbase = (size_t)blk * SS * HS;

  {
    ushort* vflat = &vt[0][0];
    for (int idx = tid; idx < 64 * 148 / 4; idx += 256)
      *(ushort4*)(vflat + idx * 4) = make_ushort4(0, 0, 0, 0);
  }
  __syncthreads();
  for (int idx = tid; idx < 144 * 16; idx += 256) {
    int s = idx >> 4, c = (idx & 15) * 4;
    if (s < SS) {
      *(ushort4*)&qs[s][c] = *(const ushort4*)(qg + gbase + s * HS + c);
      *(ushort4*)&ks[s][c] = *(const ushort4*)(kg + gbase + s * HS + c);
      ushort4 v4 = *(const ushort4*)(vg + gbase + s * HS + c);
      vt[c][s] = v4.x; vt[c + 1][s] = v4.y; vt[c + 2][s] = v4.z; vt[c + 3][s] = v4.w;
    } else {
      *(ushort4*)&qs[s][c] = make_ushort4(0, 0, 0, 0);
      *(ushort4*)&ks[s][c] = make_ushort4(0, 0, 0, 0);
    }
  }
  __syncthreads();

#pragma unroll
  for (int ti = 0; ti < 3; ++ti) {
    const int t = (ti == 0) ? (8 - wv)
                : (ti == 1) ? ((wv == 3) ? 4 : (wv + 1))
                            : ((wv == 3) ? 0 : -1);
    if (t < 0) continue;
    const int q0 = t * 16;

    bf16x8 bq[2];
#pragma unroll
    for (int k2 = 0; k2 < 2; ++k2)
      bq[k2] = mk8(*(const ushort4*)&qs[q0 + lo][k2 * 32 + 4 * hi],
                   *(const ushort4*)&qs[q0 + lo][k2 * 32 + 16 + 4 * hi]);

    f32x4 sc[9];
#pragma unroll
    for (int n = 0; n < 9; ++n) sc[n] = (f32x4)0.0f;
#pragma unroll
    for (int n = 0; n < 9; ++n) {
      if (n > t) continue;
#pragma unroll
      for (int k2 = 0; k2 < 2; ++k2) {
        bf16x8 ak = mk8(*(const ushort4*)&ks[n * 16 + lo][k2 * 32 + 4 * hi],
                        *(const ushort4*)&ks[n * 16 + lo][k2 * 32 + 16 + 4 * hi]);
        sc[n] = __builtin_amdgcn_mfma_f32_16x16x32_bf16(ak, bq[k2], sc[n], 0, 0, 0);
      }
    }

    const int qi = q0 + lo;
    float mx = -INFINITY;
#pragma unroll
    for (int n = 0; n < 9; ++n) {
      if (n > t) continue;
#pragma unroll
      for (int r = 0; r < 4; ++r) {
        int kj = n * 16 + 4 * hi + r;
        float v = (kj <= qi) ? sc[n][r] * 0.125f : -INFINITY;
        sc[n][r] = v;
        mx = fmaxf(mx, v);
      }
    }
    mx = fmaxf(mx, __shfl_xor(mx, 16));
    mx = fmaxf(mx, __shfl_xor(mx, 32));
    float sum = 0.f;
#pragma unroll
    for (int n = 0; n < 9; ++n) {
      if (n > t) continue;
#pragma unroll
      for (int r = 0; r < 4; ++r) {
        float e = __expf(sc[n][r] - mx);
        sc[n][r] = e;
        sum += e;
      }
    }
    sum += __shfl_xor(sum, 16);
    sum += __shfl_xor(sum, 32);
    const float inv = 1.0f / sum;

    f32x4 oac[4];
#pragma unroll
    for (int m = 0; m < 4; ++m) oac[m] = (f32x4)0.0f;
#pragma unroll
    for (int s2 = 0; s2 < 5; ++s2) {
      if (s2 > (t >> 1)) continue;
      const int kt1ok = (2 * s2 + 1 <= t);
      bf16x8 pb;
#pragma unroll
      for (int e = 0; e < 4; ++e) pb[e] = (short)f2bf(sc[2 * s2][e] * inv);
      if (kt1ok) {
#pragma unroll
        for (int e = 0; e < 4; ++e) pb[e + 4] = (short)f2bf(sc[2 * s2 + 1][e] * inv);
      } else {
#pragma unroll
        for (int e = 0; e < 4; ++e) pb[e + 4] = 0;
      }
#pragma unroll
      for (int m = 0; m < 4; ++m) {
        ushort4 a0 = *(const ushort4*)&vt[m * 16 + lo][32 * s2 + 4 * hi];
        ushort4 a1 = kt1ok ? *(const ushort4*)&vt[m * 16 + lo][32 * s2 + 16 + 4 * hi]
                           : make_ushort4(0, 0, 0, 0);
        oac[m] = __builtin_amdgcn_mfma_f32_16x16x32_bf16(mk8(a0, a1), pb, oac[m], 0, 0, 0);
      }
    }

    if (t < 8) {
#pragma unroll
      for (int m = 0; m < 4; ++m)
#pragma unroll
        for (int r = 0; r < 4; ++r)
          obuf[wv][lo][m * 16 + 4 * hi + r] = f2bf(oac[m][r]);
#pragma unroll
      for (int it = 0; it < 4; ++it) {
        int idx = lane + 64 * it;
        int r = idx >> 4;
        int c4 = (idx & 15) * 4;
        uint2 val = *(const uint2*)&obuf[wv][r][c4];
        int tok = g * TG + t * 16 + r;
        *(uint2*)(xo + ((size_t)(b * TT + tok)) * CC + h * HS + c4) = val;
      }
    } else {
      if (lo == 0) {
#pragma unroll
        for (int m = 0; m < 4; ++m)
#pragma unroll
          for (int r = 0; r < 4; ++r)
            attm[(size_t)blk * 64 + m * 16 + 4 * hi + r] = oac[m][r];
      }
    }
  }
}

// ---------------- second (tiny) causal attention over 15 group-mean tokens ----------------
__global__ __launch_bounds__(64) void attn2(const float* __restrict__ yq,
                                            const float* __restrict__ yk,
                                            const float* __restrict__ attm,
                                            float* __restrict__ yv) {
  __shared__ float qs2[15][64], ks2[15][64], avs[15][64], srow[16];
  int bh = blockIdx.x, lane = threadIdx.x;
  for (int j = 0; j < 15; ++j) {
    qs2[j][lane] = yq[((size_t)bh * 15 + j) * 64 + lane];
    ks2[j][lane] = yk[((size_t)bh * 15 + j) * 64 + lane];
    avs[j][lane] = attm[((size_t)bh * 16 + j) * 64 + lane];
  }
  __syncthreads();
  for (int i = 0; i < 15; ++i) {
    float qv = qs2[i][lane];
    for (int j = 0; j <= i; ++j) {
      float t = qv * ks2[j][lane];
#pragma unroll
      for (int off = 32; off > 0; off >>= 1) t += __shfl_xor(t, off);
      if (lane == 0) srow[j] = t * 0.125f;
    }
    __syncthreads();
    float mx = -INFINITY;
    for (int j = 0; j <= i; ++j) mx = fmaxf(mx, srow[j]);
    float den = 0;
    for (int j = 0; j <= i; ++j) den += __expf(srow[j] - mx);
    float inv = 1.0f / den;
    float o = 0;
    for (int j = 0; j <= i; ++j) o += __expf(srow[j] - mx) * inv * avs[j][lane];
    yv[((size_t)bh * 15 + i) * 64 + lane] = o;
    __syncthreads();
  }
}

extern "C" void kernel_launch(void* const* d_in, const int* in_sizes, int n_in,
                              void* d_out, int out_size, void* d_ws, size_t ws_size,
                              hipStream_t stream) {
  const float* x      = (const float*)d_in[0];
  const float* w_attn = (const float*)d_in[1];
  const float* w_proj = (const float*)d_in[2];
  const float* fc     = (const float*)d_in[3];
  const float* fs     = (const float*)d_in[4];
  float* out = (float*)d_out;

  char* ws = (char*)d_ws;
  ushort* xb   = (ushort*)(ws);               // x bf16; dead after qkv gemm
  ushort* xo   = (ushort*)(ws);               // reuse xb region (attn1 output)
  ushort* wab  = (ushort*)(ws + 16777216);    // dead after qkv gemm
  float*  attm = (float*) (ws + 16777216);    // reuse wab region
  ushort* wpb  = (ushort*)(ws + 23068672);
  ushort* qg   = (ushort*)(ws + 25165824);    // (B,H,G,129,64) bf16
  ushort* kg   = (ushort*)(ws + 42074112);
  ushort* vg   = (ushort*)(ws + 58982400);    // end 75,890,688

  float* yq = out + 8388608;
  float* yk = out + 8450048;
  float* yv = out + 8511488;

  cvt_f32_bf16<<<2048, 256, 0, stream>>>(x, xb, 8388608 / 4);
  cvt_f32_bf16<<<1024, 256, 0, stream>>>(w_attn, wab, 3145728 / 4);
  cvt_f32_bf16<<<512, 256, 0, stream>>>(w_proj, wpb, 1048576 / 4);
  gemm_qkv_rope<<<dim3(24, 64), 256, 0, stream>>>(xb, wab, fc, fs, qg, kg, vg, yq, yk);
  attn1<<<1024, 256, 0, stream>>>(qg, kg, vg, xo, attm);
  attn2<<<64, 64, 0, stream>>>(yq, yk, attm, yv);
  gemm_bt<false><<<dim3(8, 64), 256, 0, stream>>>(xo, wpb, out, 8192, 1024, 1024);
}

// Round 7
// 207.060 us; speedup vs baseline: 1.0983x; 1.0837x over previous
//
#include <hip/hip_runtime.h>
#include <hip/hip_bf16.h>

#define HS 64
#define NH 16
#define NG 16
#define TT 2048
#define CC 1024
#define BBATCH 4
#define TG 128
#define SS 129   // TG+1

typedef __attribute__((ext_vector_type(8))) short bf16x8;
typedef __attribute__((ext_vector_type(4))) float f32x4;

__device__ __forceinline__ float bf2f(ushort u) {
  return __uint_as_float(((unsigned)u) << 16);
}
__device__ __forceinline__ ushort f2bf(float f) {
  unsigned x = __float_as_uint(f);
  x += 0x7fff + ((x >> 16) & 1);
  return (ushort)(x >> 16);
}
__device__ __forceinline__ bf16x8 mk8(ushort4 a0, ushort4 a1) {
  bf16x8 v;
  v[0] = (short)a0.x; v[1] = (short)a0.y; v[2] = (short)a0.z; v[3] = (short)a0.w;
  v[4] = (short)a1.x; v[5] = (short)a1.y; v[6] = (short)a1.z; v[7] = (short)a1.w;
  return v;
}
__device__ __forceinline__ void load_lds16(const ushort* g, ushort* l) {
  __builtin_amdgcn_global_load_lds((const __attribute__((address_space(1))) unsigned int*)g,
                                   (__attribute__((address_space(3))) unsigned int*)l, 16, 0, 0);
}

// ---------------- fp32 -> bf16 convert ----------------
__global__ void cvt_f32_bf16(const float* __restrict__ src, ushort* __restrict__ dst, int n4) {
  int stride = gridDim.x * blockDim.x;
  for (int i = blockIdx.x * blockDim.x + threadIdx.x; i < n4; i += stride) {
    float4 v = ((const float4*)src)[i];
    ushort4 o;
    o.x = f2bf(v.x); o.y = f2bf(v.y); o.z = f2bf(v.z); o.w = f2bf(v.w);
    ((ushort4*)dst)[i] = o;
  }
}

// ---------------- GEMM mainloop core (128x128 tile, BK=64, global_load_lds) ----------------
// Both A/B frag reads use the same contiguous-k slot permutation -> cancels in MFMA.
#define GEMM_CORE(A_, B_, K_, m0_, n0_)                                            \
  {                                                                                \
    const int rA = tid >> 3, cA = (tid & 7) * 8;                                   \
    for (int k0 = 0; k0 < (K_); k0 += 64) {                                        \
      _Pragma("unroll")                                                            \
      for (int it = 0; it < 4; ++it) {                                             \
        load_lds16((A_) + (size_t)((m0_) + it * 32 + rA) * (K_) + k0 + cA,         \
                   As + it * 2048 + wv * 512);                                     \
        load_lds16((B_) + (size_t)((n0_) + it * 32 + rA) * (K_) + k0 + cA,         \
                   Bs + it * 2048 + wv * 512);                                     \
      }                                                                            \
      __syncthreads();                                                             \
      _Pragma("unroll")                                                            \
      for (int kk = 0; kk < 64; kk += 32) {                                        \
        bf16x8 af[4], bfr[4];                                                      \
        _Pragma("unroll")                                                          \
        for (int i = 0; i < 4; ++i)                                                \
          af[i] = *(const bf16x8*)(As + (wr * 64 + i * 16 + lo) * 64 + kk + 8 * hi); \
        _Pragma("unroll")                                                          \
        for (int j = 0; j < 4; ++j)                                                \
          bfr[j] = *(const bf16x8*)(Bs + (wc * 64 + j * 16 + lo) * 64 + kk + 8 * hi); \
        _Pragma("unroll")                                                          \
        for (int i = 0; i < 4; ++i)                                                \
          _Pragma("unroll")                                                        \
          for (int j = 0; j < 4; ++j)                                              \
            acc[i][j] = __builtin_amdgcn_mfma_f32_16x16x32_bf16(af[i], bfr[j], acc[i][j], 0, 0, 0); \
      }                                                                            \
      __syncthreads();                                                             \
    }                                                                              \
  }

// ---------------- plain bf16 GEMM:  C[m][n] = sum_k A[m][k] * Bw[n][k] ----------------
template <bool OUT_BF16>
__global__ __launch_bounds__(256) void gemm_bt(const ushort* __restrict__ A,
                                               const ushort* __restrict__ Bw,
                                               void* __restrict__ Cout,
                                               int M, int N, int K) {
  __shared__ ushort As[128 * 64];
  __shared__ ushort Bs[128 * 64];
  const int m0 = blockIdx.y * 128;
  const int n0 = blockIdx.x * 128;
  const int tid = threadIdx.x;
  const int lane = tid & 63;
  const int wv = tid >> 6;
  const int wr = wv >> 1, wc = wv & 1;
  const int lo = lane & 15, hi = lane >> 4;

  f32x4 acc[4][4];
#pragma unroll
  for (int i = 0; i < 4; ++i)
#pragma unroll
    for (int j = 0; j < 4; ++j) acc[i][j] = (f32x4)0.0f;

  GEMM_CORE(A, Bw, K, m0, n0)

#pragma unroll
  for (int i = 0; i < 4; ++i) {
    int row = m0 + wr * 64 + i * 16 + 4 * hi;
#pragma unroll
    for (int j = 0; j < 4; ++j) {
      int col = n0 + wc * 64 + j * 16 + lo;
#pragma unroll
      for (int r = 0; r < 4; ++r) {
        float v = acc[i][j][r];
        if constexpr (OUT_BF16) {
          ((ushort*)Cout)[(size_t)(row + r) * N + col] = f2bf(v);
        } else {
          ((float*)Cout)[(size_t)(row + r) * N + col] = v;
        }
      }
    }
  }
}

// ---------------- qkv GEMM with fused RoPE + regroup + per-group mean ----------------
// Tile 128 rows = one (b, g) group; 128 cols = 2 heads of one of {q,k,v}.
// Epilogue: per head pass, fp32 acc -> LDS, then coalesced pass applies RoPE on fp32
// (single bf16 rounding) with float4 cos/sin loads + fp32 column partials for the mean.
__global__ __launch_bounds__(256) void gemm_qkv_rope(const ushort* __restrict__ A,
                                                     const ushort* __restrict__ Bw,
                                                     const float* __restrict__ fc,
                                                     const float* __restrict__ fs,
                                                     ushort* __restrict__ qg,
                                                     ushort* __restrict__ kg,
                                                     ushort* __restrict__ vg,
                                                     float* __restrict__ yq,
                                                     float* __restrict__ yk) {
  __shared__ __align__(16) ushort smem[2 * 128 * 68];  // mainloop As|Bs 32KB; epilogue epif[128][68] fp32 34.8KB
  __shared__ float colsum[4][8][16];                   // [wave][c-group][hh*8+e]
  ushort* As = smem;
  ushort* Bs = smem + 128 * 64;
  typedef float epif_row[68];
  epif_row* epif = reinterpret_cast<epif_row*>(smem);

  const int K = CC, m0 = blockIdx.y * 128, n0 = blockIdx.x * 128;
  const int tid = threadIdx.x;
  const int lane = tid & 63;
  const int wv = tid >> 6;
  const int wr = wv >> 1, wc = wv & 1;
  const int lo = lane & 15, hi = lane >> 4;

  f32x4 acc[4][4];
#pragma unroll
  for (int i = 0; i < 4; ++i)
#pragma unroll
    for (int j = 0; j < 4; ++j) acc[i][j] = (f32x4)0.0f;

  GEMM_CORE(A, Bw, K, m0, n0)
  // trailing __syncthreads in GEMM_CORE: all waves done with As/Bs -> safe to alias as epif

  const int b = m0 >> 11;          // m0 / 2048
  const int tseq0 = m0 & 2047;     // g*128
  const int g = tseq0 >> 7;
  const int part = n0 >> 10;       // 0=q 1=k 2=v
  const int cbase = n0 & 1023;
  const int h0 = cbase >> 6;       // first head of this tile
  ushort* G = part == 0 ? qg : (part == 1 ? kg : vg);

  const int r0 = tid >> 3;            // 0..31
  const int c8 = (tid & 7) * 8;       // 0..56 (d base, 8 consecutive d per thread)
  float ms[2][8];
#pragma unroll
  for (int hh = 0; hh < 2; ++hh)
#pragma unroll
    for (int e = 0; e < 8; ++e) ms[hh][e] = 0.f;

#pragma unroll
  for (int hh = 0; hh < 2; ++hh) {
    // phase 1: waves owning head hh dump fp32 acc into epif
    if (wc == hh) {
#pragma unroll
      for (int j = 0; j < 4; ++j) {
        const int dcol = j * 16 + lo;
#pragma unroll
        for (int i = 0; i < 4; ++i)
#pragma unroll
          for (int r = 0; r < 4; ++r)
            epif[wr * 64 + i * 16 + 4 * hi + r][dcol] = acc[i][j][r];
      }
    }
    __syncthreads();

    // phase 2: coalesced rope + store + mean partials
#pragma unroll
    for (int it = 0; it < 4; ++it) {
      const int r = r0 + 32 * it;
      float4 va = *(const float4*)&epif[r][c8];
      float4 vb = *(const float4*)&epif[r][c8 + 4];
      float v0 = va.x, v1 = va.y, v2 = va.z, v3 = va.w;
      float v4 = vb.x, v5 = vb.y, v6 = vb.z, v7 = vb.w;
      if (part < 2) {
        const int ts = tseq0 + r;
        float4 cv = *(const float4*)&fc[ts * 32 + (c8 >> 1)];
        float4 sv = *(const float4*)&fs[ts * 32 + (c8 >> 1)];
        float o0 = v0 * cv.x - v1 * sv.x, o1 = v0 * sv.x + v1 * cv.x;
        float o2 = v2 * cv.y - v3 * sv.y, o3 = v2 * sv.y + v3 * cv.y;
        float o4 = v4 * cv.z - v5 * sv.z, o5 = v4 * sv.z + v5 * cv.z;
        float o6 = v6 * cv.w - v7 * sv.w, o7 = v6 * sv.w + v7 * cv.w;
        v0 = o0; v1 = o1; v2 = o2; v3 = o3; v4 = o4; v5 = o5; v6 = o6; v7 = o7;
      }
      ms[hh][0] += v0; ms[hh][1] += v1; ms[hh][2] += v2; ms[hh][3] += v3;
      ms[hh][4] += v4; ms[hh][5] += v5; ms[hh][6] += v6; ms[hh][7] += v7;
      uint4 o;
      o.x = (unsigned)f2bf(v0) | ((unsigned)f2bf(v1) << 16);
      o.y = (unsigned)f2bf(v2) | ((unsigned)f2bf(v3) << 16);
      o.z = (unsigned)f2bf(v4) | ((unsigned)f2bf(v5) << 16);
      o.w = (unsigned)f2bf(v6) | ((unsigned)f2bf(v7) << 16);
      const int blk = (b * 16 + h0 + hh) * 16 + g;
      *(uint4*)(G + ((size_t)blk * SS + r) * 64 + c8) = o;
    }
    __syncthreads();
  }

  // phase 3: mean reduction (shfl over r0 within wave, LDS across waves)
#pragma unroll
  for (int e = 0; e < 8; ++e) {
    float s0 = ms[0][e], s1 = ms[1][e];
    s0 += __shfl_xor(s0, 8);  s1 += __shfl_xor(s1, 8);
    s0 += __shfl_xor(s0, 16); s1 += __shfl_xor(s1, 16);
    s0 += __shfl_xor(s0, 32); s1 += __shfl_xor(s1, 32);
    if ((lane >> 3) == 0) {
      colsum[wv][lane][e] = s0;
      colsum[wv][lane][8 + e] = s1;
    }
  }
  __syncthreads();
  if (tid < 128) {
    const int hh = tid >> 6, dcol = tid & 63;
    const int cg = dcol >> 3, e = dcol & 7;
    const float s = colsum[0][cg][hh * 8 + e] + colsum[1][cg][hh * 8 + e] +
                    colsum[2][cg][hh * 8 + e] + colsum[3][cg][hh * 8 + e];
    const float mean = s * (1.0f / 128.0f);
    const int h = h0 + hh;
    const int blk = (b * 16 + h) * 16 + g;
    G[((size_t)blk * SS + 128) * 64 + dcol] = f2bf(mean);
    if (g < 15 && part < 2) {
      float* Y = (part == 0) ? yq : yk;
      Y[((size_t)(b * 16 + h) * 15 + g) * 64 + dcol] = mean;
    }
  }
}

// ---------------- causal attention per (b,h,g), S=129, d=64 — MFMA version ----------------
__global__ __launch_bounds__(256) void attn1(const ushort* __restrict__ qg,
                                             const ushort* __restrict__ kg,
                                             const ushort* __restrict__ vg,
                                             ushort* __restrict__ xo, float* __restrict__ attm) {
  __shared__ ushort qs[144][68];
  __shared__ ushort ks[144][68];
  __shared__ ushort vt[64][148];   // V^T: vt[d][key]
  __shared__ ushort obuf[4][16][68];
  const int blk = blockIdx.x;
  const int g = blk & 15, h = (blk >> 4) & 15, b = blk >> 8;
  const int tid = threadIdx.x;
  const int lane = tid & 63, wv = tid >> 6;
  const int lo = lane & 15, hi = lane >> 4;
  const size_t gbase = (size_t)blk * SS * HS;

  {
    ushort* vflat = &vt[0][0];
    for (int idx = tid; idx < 64 * 148 / 4; idx += 256)
      *(ushort4*)(vflat + idx * 4) = make_ushort4(0, 0, 0, 0);
  }
  __syncthreads();
  for (int idx = tid; idx < 144 * 16; idx += 256) {
    int s = idx >> 4, c = (idx & 15) * 4;
    if (s < SS) {
      *(ushort4*)&qs[s][c] = *(const ushort4*)(qg + gbase + s * HS + c);
      *(ushort4*)&ks[s][c] = *(const ushort4*)(kg + gbase + s * HS + c);
      ushort4 v4 = *(const ushort4*)(vg + gbase + s * HS + c);
      vt[c][s] = v4.x; vt[c + 1][s] = v4.y; vt[c + 2][s] = v4.z; vt[c + 3][s] = v4.w;
    } else {
      *(ushort4*)&qs[s][c] = make_ushort4(0, 0, 0, 0);
      *(ushort4*)&ks[s][c] = make_ushort4(0, 0, 0, 0);
    }
  }
  __syncthreads();

#pragma unroll
  for (int ti = 0; ti < 3; ++ti) {
    const int t = (ti == 0) ? (8 - wv)
                : (ti == 1) ? ((wv == 3) ? 4 : (wv + 1))
                            : ((wv == 3) ? 0 : -1);
    if (t < 0) continue;
    const int q0 = t * 16;

    bf16x8 bq[2];
#pragma unroll
    for (int k2 = 0; k2 < 2; ++k2)
      bq[k2] = mk8(*(const ushort4*)&qs[q0 + lo][k2 * 32 + 4 * hi],
                   *(const ushort4*)&qs[q0 + lo][k2 * 32 + 16 + 4 * hi]);

    f32x4 sc[9];
#pragma unroll
    for (int n = 0; n < 9; ++n) sc[n] = (f32x4)0.0f;
#pragma unroll
    for (int n = 0; n < 9; ++n) {
      if (n > t) continue;
#pragma unroll
      for (int k2 = 0; k2 < 2; ++k2) {
        bf16x8 ak = mk8(*(const ushort4*)&ks[n * 16 + lo][k2 * 32 + 4 * hi],
                        *(const ushort4*)&ks[n * 16 + lo][k2 * 32 + 16 + 4 * hi]);
        sc[n] = __builtin_amdgcn_mfma_f32_16x16x32_bf16(ak, bq[k2], sc[n], 0, 0, 0);
      }
    }

    const int qi = q0 + lo;
    float mx = -INFINITY;
#pragma unroll
    for (int n = 0; n < 9; ++n) {
      if (n > t) continue;
#pragma unroll
      for (int r = 0; r < 4; ++r) {
        int kj = n * 16 + 4 * hi + r;
        float v = (kj <= qi) ? sc[n][r] * 0.125f : -INFINITY;
        sc[n][r] = v;
        mx = fmaxf(mx, v);
      }
    }
    mx = fmaxf(mx, __shfl_xor(mx, 16));
    mx = fmaxf(mx, __shfl_xor(mx, 32));
    float sum = 0.f;
#pragma unroll
    for (int n = 0; n < 9; ++n) {
      if (n > t) continue;
#pragma unroll
      for (int r = 0; r < 4; ++r) {
        float e = __expf(sc[n][r] - mx);
        sc[n][r] = e;
        sum += e;
      }
    }
    sum += __shfl_xor(sum, 16);
    sum += __shfl_xor(sum, 32);
    const float inv = 1.0f / sum;

    f32x4 oac[4];
#pragma unroll
    for (int m = 0; m < 4; ++m) oac[m] = (f32x4)0.0f;
#pragma unroll
    for (int s2 = 0; s2 < 5; ++s2) {
      if (s2 > (t >> 1)) continue;
      const int kt1ok = (2 * s2 + 1 <= t);
      bf16x8 pb;
#pragma unroll
      for (int e = 0; e < 4; ++e) pb[e] = (short)f2bf(sc[2 * s2][e] * inv);
      if (kt1ok) {
#pragma unroll
        for (int e = 0; e < 4; ++e) pb[e + 4] = (short)f2bf(sc[2 * s2 + 1][e] * inv);
      } else {
#pragma unroll
        for (int e = 0; e < 4; ++e) pb[e + 4] = 0;
      }
#pragma unroll
      for (int m = 0; m < 4; ++m) {
        ushort4 a0 = *(const ushort4*)&vt[m * 16 + lo][32 * s2 + 4 * hi];
        ushort4 a1 = kt1ok ? *(const ushort4*)&vt[m * 16 + lo][32 * s2 + 16 + 4 * hi]
                           : make_ushort4(0, 0, 0, 0);
        oac[m] = __builtin_amdgcn_mfma_f32_16x16x32_bf16(mk8(a0, a1), pb, oac[m], 0, 0, 0);
      }
    }

    if (t < 8) {
#pragma unroll
      for (int m = 0; m < 4; ++m)
#pragma unroll
        for (int r = 0; r < 4; ++r)
          obuf[wv][lo][m * 16 + 4 * hi + r] = f2bf(oac[m][r]);
#pragma unroll
      for (int it = 0; it < 4; ++it) {
        int idx = lane + 64 * it;
        int r = idx >> 4;
        int c4 = (idx & 15) * 4;
        uint2 val = *(const uint2*)&obuf[wv][r][c4];
        int tok = g * TG + t * 16 + r;
        *(uint2*)(xo + ((size_t)(b * TT + tok)) * CC + h * HS + c4) = val;
      }
    } else {
      if (lo == 0) {
#pragma unroll
        for (int m = 0; m < 4; ++m)
#pragma unroll
          for (int r = 0; r < 4; ++r)
            attm[(size_t)blk * 64 + m * 16 + 4 * hi + r] = oac[m][r];
      }
    }
  }
}

// ---------------- second (tiny) causal attention over 15 group-mean tokens ----------------
__global__ __launch_bounds__(64) void attn2(const float* __restrict__ yq,
                                            const float* __restrict__ yk,
                                            const float* __restrict__ attm,
                                            float* __restrict__ yv) {
  __shared__ float qs2[15][64], ks2[15][64], avs[15][64], srow[16];
  int bh = blockIdx.x, lane = threadIdx.x;
  for (int j = 0; j < 15; ++j) {
    qs2[j][lane] = yq[((size_t)bh * 15 + j) * 64 + lane];
    ks2[j][lane] = yk[((size_t)bh * 15 + j) * 64 + lane];
    avs[j][lane] = attm[((size_t)bh * 16 + j) * 64 + lane];
  }
  __syncthreads();
  for (int i = 0; i < 15; ++i) {
    float qv = qs2[i][lane];
    for (int j = 0; j <= i; ++j) {
      float t = qv * ks2[j][lane];
#pragma unroll
      for (int off = 32; off > 0; off >>= 1) t += __shfl_xor(t, off);
      if (lane == 0) srow[j] = t * 0.125f;
    }
    __syncthreads();
    float mx = -INFINITY;
    for (int j = 0; j <= i; ++j) mx = fmaxf(mx, srow[j]);
    float den = 0;
    for (int j = 0; j <= i; ++j) den += __expf(srow[j] - mx);
    float inv = 1.0f / den;
    float o = 0;
    for (int j = 0; j <= i; ++j) o += __expf(srow[j] - mx) * inv * avs[j][lane];
    yv[((size_t)bh * 15 + i) * 64 + lane] = o;
    __syncthreads();
  }
}

extern "C" void kernel_launch(void* const* d_in, const int* in_sizes, int n_in,
                              void* d_out, int out_size, void* d_ws, size_t ws_size,
                              hipStream_t stream) {
  const float* x      = (const float*)d_in[0];
  const float* w_attn = (const float*)d_in[1];
  const float* w_proj = (const float*)d_in[2];
  const float* fc     = (const float*)d_in[3];
  const float* fs     = (const float*)d_in[4];
  float* out = (float*)d_out;

  char* ws = (char*)d_ws;
  ushort* xb   = (ushort*)(ws);               // x bf16; dead after qkv gemm
  ushort* xo   = (ushort*)(ws);               // reuse xb region (attn1 output)
  ushort* wab  = (ushort*)(ws + 16777216);    // dead after qkv gemm
  float*  attm = (float*) (ws + 16777216);    // reuse wab region
  ushort* wpb  = (ushort*)(ws + 23068672);
  ushort* qg   = (ushort*)(ws + 25165824);    // (B,H,G,129,64) bf16
  ushort* kg   = (ushort*)(ws + 42074112);
  ushort* vg   = (ushort*)(ws + 58982400);    // end 75,890,688

  float* yq = out + 8388608;
  float* yk = out + 8450048;
  float* yv = out + 8511488;

  cvt_f32_bf16<<<2048, 256, 0, stream>>>(x, xb, 8388608 / 4);
  cvt_f32_bf16<<<1024, 256, 0, stream>>>(w_attn, wab, 3145728 / 4);
  cvt_f32_bf16<<<512, 256, 0, stream>>>(w_proj, wpb, 1048576 / 4);
  gemm_qkv_rope<<<dim3(24, 64), 256, 0, stream>>>(xb, wab, fc, fs, qg, kg, vg, yq, yk);
  attn1<<<1024, 256, 0, stream>>>(qg, kg, vg, xo, attm);
  attn2<<<64, 64, 0, stream>>>(yq, yk, attm, yv);
  gemm_bt<false><<<dim3(8, 64), 256, 0, stream>>>(xo, wpb, out, 8192, 1024, 1024);
}

// Round 8
// 205.631 us; speedup vs baseline: 1.1059x; 1.0070x over previous
//
#include <hip/hip_runtime.h>
#include <hip/hip_bf16.h>

#define HS 64
#define NH 16
#define NG 16
#define TT 2048
#define CC 1024
#define BBATCH 4
#define TG 128
#define SS 129   // TG+1

typedef __attribute__((ext_vector_type(8))) short bf16x8;
typedef __attribute__((ext_vector_type(4))) float f32x4;

__device__ __forceinline__ float bf2f(ushort u) {
  return __uint_as_float(((unsigned)u) << 16);
}
__device__ __forceinline__ ushort f2bf(float f) {
  unsigned x = __float_as_uint(f);
  x += 0x7fff + ((x >> 16) & 1);
  return (ushort)(x >> 16);
}
__device__ __forceinline__ bf16x8 mk8(ushort4 a0, ushort4 a1) {
  bf16x8 v;
  v[0] = (short)a0.x; v[1] = (short)a0.y; v[2] = (short)a0.z; v[3] = (short)a0.w;
  v[4] = (short)a1.x; v[5] = (short)a1.y; v[6] = (short)a1.z; v[7] = (short)a1.w;
  return v;
}
__device__ __forceinline__ void load_lds16(const ushort* g, ushort* l) {
  __builtin_amdgcn_global_load_lds((const __attribute__((address_space(1))) unsigned int*)g,
                                   (__attribute__((address_space(3))) unsigned int*)l, 16, 0, 0);
}

// ---------------- fp32 -> bf16 convert ----------------
__global__ void cvt_f32_bf16(const float* __restrict__ src, ushort* __restrict__ dst, int n4) {
  int stride = gridDim.x * blockDim.x;
  for (int i = blockIdx.x * blockDim.x + threadIdx.x; i < n4; i += stride) {
    float4 v = ((const float4*)src)[i];
    ushort4 o;
    o.x = f2bf(v.x); o.y = f2bf(v.y); o.z = f2bf(v.z); o.w = f2bf(v.w);
    ((ushort4*)dst)[i] = o;
  }
}

// ---------------- GEMM mainloop core (128x128 tile, BK=64, global_load_lds) ----------------
// Both A/B frag reads use the same contiguous-k slot permutation -> cancels in MFMA.
#define GEMM_CORE(A_, B_, K_, m0_, n0_)                                            \
  {                                                                                \
    const int rA = tid >> 3, cA = (tid & 7) * 8;                                   \
    for (int k0 = 0; k0 < (K_); k0 += 64) {                                        \
      _Pragma("unroll")                                                            \
      for (int it = 0; it < 4; ++it) {                                             \
        load_lds16((A_) + (size_t)((m0_) + it * 32 + rA) * (K_) + k0 + cA,         \
                   As + it * 2048 + wv * 512);                                     \
        load_lds16((B_) + (size_t)((n0_) + it * 32 + rA) * (K_) + k0 + cA,         \
                   Bs + it * 2048 + wv * 512);                                     \
      }                                                                            \
      __syncthreads();                                                             \
      _Pragma("unroll")                                                            \
      for (int kk = 0; kk < 64; kk += 32) {                                        \
        bf16x8 af[4], bfr[4];                                                      \
        _Pragma("unroll")                                                          \
        for (int i = 0; i < 4; ++i)                                                \
          af[i] = *(const bf16x8*)(As + (wr * 64 + i * 16 + lo) * 64 + kk + 8 * hi); \
        _Pragma("unroll")                                                          \
        for (int j = 0; j < 4; ++j)                                                \
          bfr[j] = *(const bf16x8*)(Bs + (wc * 64 + j * 16 + lo) * 64 + kk + 8 * hi); \
        _Pragma("unroll")                                                          \
        for (int i = 0; i < 4; ++i)                                                \
          _Pragma("unroll")                                                        \
          for (int j = 0; j < 4; ++j)                                              \
            acc[i][j] = __builtin_amdgcn_mfma_f32_16x16x32_bf16(af[i], bfr[j], acc[i][j], 0, 0, 0); \
      }                                                                            \
      __syncthreads();                                                             \
    }                                                                              \
  }

// ---------------- plain bf16 GEMM:  C[m][n] = sum_k A[m][k] * Bw[n][k] ----------------
template <bool OUT_BF16>
__global__ __launch_bounds__(256) void gemm_bt(const ushort* __restrict__ A,
                                               const ushort* __restrict__ Bw,
                                               void* __restrict__ Cout,
                                               int M, int N, int K) {
  __shared__ ushort As[128 * 64];
  __shared__ ushort Bs[128 * 64];
  const int m0 = blockIdx.y * 128;
  const int n0 = blockIdx.x * 128;
  const int tid = threadIdx.x;
  const int lane = tid & 63;
  const int wv = tid >> 6;
  const int wr = wv >> 1, wc = wv & 1;
  const int lo = lane & 15, hi = lane >> 4;

  f32x4 acc[4][4];
#pragma unroll
  for (int i = 0; i < 4; ++i)
#pragma unroll
    for (int j = 0; j < 4; ++j) acc[i][j] = (f32x4)0.0f;

  GEMM_CORE(A, Bw, K, m0, n0)

#pragma unroll
  for (int i = 0; i < 4; ++i) {
    int row = m0 + wr * 64 + i * 16 + 4 * hi;
#pragma unroll
    for (int j = 0; j < 4; ++j) {
      int col = n0 + wc * 64 + j * 16 + lo;
#pragma unroll
      for (int r = 0; r < 4; ++r) {
        float v = acc[i][j][r];
        if constexpr (OUT_BF16) {
          ((ushort*)Cout)[(size_t)(row + r) * N + col] = f2bf(v);
        } else {
          ((float*)Cout)[(size_t)(row + r) * N + col] = v;
        }
      }
    }
  }
}

// ---------------- qkv GEMM with fused RoPE + regroup + per-group mean ----------------
// Tile 128 rows = one (b, g) group; 128 cols = 2 heads of one of {q,k,v}.
// Epilogue: per head pass, fp32 acc -> LDS, then coalesced pass applies RoPE on fp32
// (single bf16 rounding) with float4 cos/sin loads + fp32 column partials for the mean.
__global__ __launch_bounds__(256) void gemm_qkv_rope(const ushort* __restrict__ A,
                                                     const ushort* __restrict__ Bw,
                                                     const float* __restrict__ fc,
                                                     const float* __restrict__ fs,
                                                     ushort* __restrict__ qg,
                                                     ushort* __restrict__ kg,
                                                     ushort* __restrict__ vg,
                                                     float* __restrict__ yq,
                                                     float* __restrict__ yk) {
  __shared__ __align__(16) ushort smem[2 * 128 * 68];  // mainloop As|Bs 32KB; epilogue epif[128][68] fp32 34.8KB
  __shared__ float colsum[4][8][16];                   // [wave][c-group][hh*8+e]
  ushort* As = smem;
  ushort* Bs = smem + 128 * 64;
  typedef float epif_row[68];
  epif_row* epif = reinterpret_cast<epif_row*>(smem);

  const int K = CC, m0 = blockIdx.y * 128, n0 = blockIdx.x * 128;
  const int tid = threadIdx.x;
  const int lane = tid & 63;
  const int wv = tid >> 6;
  const int wr = wv >> 1, wc = wv & 1;
  const int lo = lane & 15, hi = lane >> 4;

  f32x4 acc[4][4];
#pragma unroll
  for (int i = 0; i < 4; ++i)
#pragma unroll
    for (int j = 0; j < 4; ++j) acc[i][j] = (f32x4)0.0f;

  GEMM_CORE(A, Bw, K, m0, n0)
  // trailing __syncthreads in GEMM_CORE: all waves done with As/Bs -> safe to alias as epif

  const int b = m0 >> 11;          // m0 / 2048
  const int tseq0 = m0 & 2047;     // g*128
  const int g = tseq0 >> 7;
  const int part = n0 >> 10;       // 0=q 1=k 2=v
  const int cbase = n0 & 1023;
  const int h0 = cbase >> 6;       // first head of this tile
  ushort* G = part == 0 ? qg : (part == 1 ? kg : vg);

  const int r0 = tid >> 3;            // 0..31
  const int c8 = (tid & 7) * 8;       // 0..56 (d base, 8 consecutive d per thread)
  float ms[2][8];
#pragma unroll
  for (int hh = 0; hh < 2; ++hh)
#pragma unroll
    for (int e = 0; e < 8; ++e) ms[hh][e] = 0.f;

#pragma unroll
  for (int hh = 0; hh < 2; ++hh) {
    // phase 1: waves owning head hh dump fp32 acc into epif
    if (wc == hh) {
#pragma unroll
      for (int j = 0; j < 4; ++j) {
        const int dcol = j * 16 + lo;
#pragma unroll
        for (int i = 0; i < 4; ++i)
#pragma unroll
          for (int r = 0; r < 4; ++r)
            epif[wr * 64 + i * 16 + 4 * hi + r][dcol] = acc[i][j][r];
      }
    }
    __syncthreads();

    // phase 2: coalesced rope + store + mean partials
#pragma unroll
    for (int it = 0; it < 4; ++it) {
      const int r = r0 + 32 * it;
      float4 va = *(const float4*)&epif[r][c8];
      float4 vb = *(const float4*)&epif[r][c8 + 4];
      float v0 = va.x, v1 = va.y, v2 = va.z, v3 = va.w;
      float v4 = vb.x, v5 = vb.y, v6 = vb.z, v7 = vb.w;
      if (part < 2) {
        const int ts = tseq0 + r;
        float4 cv = *(const float4*)&fc[ts * 32 + (c8 >> 1)];
        float4 sv = *(const float4*)&fs[ts * 32 + (c8 >> 1)];
        float o0 = v0 * cv.x - v1 * sv.x, o1 = v0 * sv.x + v1 * cv.x;
        float o2 = v2 * cv.y - v3 * sv.y, o3 = v2 * sv.y + v3 * cv.y;
        float o4 = v4 * cv.z - v5 * sv.z, o5 = v4 * sv.z + v5 * cv.z;
        float o6 = v6 * cv.w - v7 * sv.w, o7 = v6 * sv.w + v7 * cv.w;
        v0 = o0; v1 = o1; v2 = o2; v3 = o3; v4 = o4; v5 = o5; v6 = o6; v7 = o7;
      }
      ms[hh][0] += v0; ms[hh][1] += v1; ms[hh][2] += v2; ms[hh][3] += v3;
      ms[hh][4] += v4; ms[hh][5] += v5; ms[hh][6] += v6; ms[hh][7] += v7;
      uint4 o;
      o.x = (unsigned)f2bf(v0) | ((unsigned)f2bf(v1) << 16);
      o.y = (unsigned)f2bf(v2) | ((unsigned)f2bf(v3) << 16);
      o.z = (unsigned)f2bf(v4) | ((unsigned)f2bf(v5) << 16);
      o.w = (unsigned)f2bf(v6) | ((unsigned)f2bf(v7) << 16);
      const int blk = (b * 16 + h0 + hh) * 16 + g;
      *(uint4*)(G + ((size_t)blk * SS + r) * 64 + c8) = o;
    }
    __syncthreads();
  }

  // phase 3: mean reduction (shfl over r0 within wave, LDS across waves)
#pragma unroll
  for (int e = 0; e < 8; ++e) {
    float s0 = ms[0][e], s1 = ms[1][e];
    s0 += __shfl_xor(s0, 8);  s1 += __shfl_xor(s1, 8);
    s0 += __shfl_xor(s0, 16); s1 += __shfl_xor(s1, 16);
    s0 += __shfl_xor(s0, 32); s1 += __shfl_xor(s1, 32);
    if ((lane >> 3) == 0) {
      colsum[wv][lane][e] = s0;
      colsum[wv][lane][8 + e] = s1;
    }
  }
  __syncthreads();
  if (tid < 128) {
    const int hh = tid >> 6, dcol = tid & 63;
    const int cg = dcol >> 3, e = dcol & 7;
    const float s = colsum[0][cg][hh * 8 + e] + colsum[1][cg][hh * 8 + e] +
                    colsum[2][cg][hh * 8 + e] + colsum[3][cg][hh * 8 + e];
    const float mean = s * (1.0f / 128.0f);
    const int h = h0 + hh;
    const int blk = (b * 16 + h) * 16 + g;
    G[((size_t)blk * SS + 128) * 64 + dcol] = f2bf(mean);
    if (g < 15 && part < 2) {
      float* Y = (part == 0) ? yq : yk;
      Y[((size_t)(b * 16 + h) * 15 + g) * 64 + dcol] = mean;
    }
  }
}

// ---------------- causal attention per (b,h,g), S=129, d=64 — MFMA version ----------------
// Q fragments read directly from global (each Q row consumed by exactly one wave).
// ks rows 129..143 are stale LDS; every score sourced from them lands in a masked or
// discarded (garbage-query) column. vt pad cols 128..147 zeroed (PV needs finite 0s).
__global__ __launch_bounds__(256) void attn1(const ushort* __restrict__ qg,
                                             const ushort* __restrict__ kg,
                                             const ushort* __restrict__ vg,
                                             ushort* __restrict__ xo, float* __restrict__ attm) {
  __shared__ ushort ks[144][68];
  __shared__ ushort vt[64][148];   // V^T: vt[d][key]
  __shared__ ushort obuf[4][16][68];
  const int blk = blockIdx.x;
  const int g = blk & 15, h = (blk >> 4) & 15, b = blk >> 8;
  const int tid = threadIdx.x;
  const int lane = tid & 63, wv = tid >> 6;
  const int lo = lane & 15, hi = lane >> 4;
  const size_t gbase = (size_t)blk * SS * HS;

  // zero V^T pad cols 128..147 only (keys 129..143 are read by PV with pb==0)
  for (int idx = tid; idx < 320; idx += 256) {
    int d = idx / 5, ch = (idx % 5) * 4;
    *(ushort4*)&vt[d][128 + ch] = make_ushort4(0, 0, 0, 0);
  }
  __syncthreads();
  // stage K rows 0..128 (vector) + V transposed (col 128 = mean overwrites the zero)
  for (int idx = tid; idx < SS * 16; idx += 256) {
    int s = idx >> 4, c = (idx & 15) * 4;
    *(ushort4*)&ks[s][c] = *(const ushort4*)(kg + gbase + s * HS + c);
    ushort4 v4 = *(const ushort4*)(vg + gbase + s * HS + c);
    vt[c][s] = v4.x; vt[c + 1][s] = v4.y; vt[c + 2][s] = v4.z; vt[c + 3][s] = v4.w;
  }
  __syncthreads();

#pragma unroll
  for (int ti = 0; ti < 3; ++ti) {
    const int t = (ti == 0) ? (8 - wv)
                : (ti == 1) ? ((wv == 3) ? 4 : (wv + 1))
                            : ((wv == 3) ? 0 : -1);
    if (t < 0) continue;
    const int q0 = t * 16;

    // Q B-frags direct from global (row q0+lo; t=8 rows >128 feed discarded columns)
    const ushort* qrow = qg + gbase + (size_t)(q0 + lo) * HS;
    bf16x8 bq[2];
#pragma unroll
    for (int k2 = 0; k2 < 2; ++k2)
      bq[k2] = mk8(*(const ushort4*)(qrow + k2 * 32 + 4 * hi),
                   *(const ushort4*)(qrow + k2 * 32 + 16 + 4 * hi));

    f32x4 sc[9];
#pragma unroll
    for (int n = 0; n < 9; ++n) sc[n] = (f32x4)0.0f;
#pragma unroll
    for (int n = 0; n < 9; ++n) {
      if (n > t) continue;
#pragma unroll
      for (int k2 = 0; k2 < 2; ++k2) {
        bf16x8 ak = mk8(*(const ushort4*)&ks[n * 16 + lo][k2 * 32 + 4 * hi],
                        *(const ushort4*)&ks[n * 16 + lo][k2 * 32 + 16 + 4 * hi]);
        sc[n] = __builtin_amdgcn_mfma_f32_16x16x32_bf16(ak, bq[k2], sc[n], 0, 0, 0);
      }
    }

    const int qi = q0 + lo;
    float mx = -INFINITY;
#pragma unroll
    for (int n = 0; n < 9; ++n) {
      if (n > t) continue;
#pragma unroll
      for (int r = 0; r < 4; ++r) {
        int kj = n * 16 + 4 * hi + r;
        float v = (kj <= qi) ? sc[n][r] * 0.125f : -INFINITY;
        sc[n][r] = v;
        mx = fmaxf(mx, v);
      }
    }
    mx = fmaxf(mx, __shfl_xor(mx, 16));
    mx = fmaxf(mx, __shfl_xor(mx, 32));
    float sum = 0.f;
#pragma unroll
    for (int n = 0; n < 9; ++n) {
      if (n > t) continue;
#pragma unroll
      for (int r = 0; r < 4; ++r) {
        float e = __expf(sc[n][r] - mx);
        sc[n][r] = e;
        sum += e;
      }
    }
    sum += __shfl_xor(sum, 16);
    sum += __shfl_xor(sum, 32);
    const float inv = 1.0f / sum;

    f32x4 oac[4];
#pragma unroll
    for (int m = 0; m < 4; ++m) oac[m] = (f32x4)0.0f;
#pragma unroll
    for (int s2 = 0; s2 < 5; ++s2) {
      if (s2 > (t >> 1)) continue;
      const int kt1ok = (2 * s2 + 1 <= t);
      bf16x8 pb;
#pragma unroll
      for (int e = 0; e < 4; ++e) pb[e] = (short)f2bf(sc[2 * s2][e] * inv);
      if (kt1ok) {
#pragma unroll
        for (int e = 0; e < 4; ++e) pb[e + 4] = (short)f2bf(sc[2 * s2 + 1][e] * inv);
      } else {
#pragma unroll
        for (int e = 0; e < 4; ++e) pb[e + 4] = 0;
      }
#pragma unroll
      for (int m = 0; m < 4; ++m) {
        ushort4 a0 = *(const ushort4*)&vt[m * 16 + lo][32 * s2 + 4 * hi];
        ushort4 a1 = kt1ok ? *(const ushort4*)&vt[m * 16 + lo][32 * s2 + 16 + 4 * hi]
                           : make_ushort4(0, 0, 0, 0);
        oac[m] = __builtin_amdgcn_mfma_f32_16x16x32_bf16(mk8(a0, a1), pb, oac[m], 0, 0, 0);
      }
    }

    if (t < 8) {
#pragma unroll
      for (int m = 0; m < 4; ++m)
#pragma unroll
        for (int r = 0; r < 4; ++r)
          obuf[wv][lo][m * 16 + 4 * hi + r] = f2bf(oac[m][r]);
#pragma unroll
      for (int it = 0; it < 4; ++it) {
        int idx = lane + 64 * it;
        int r = idx >> 4;
        int c4 = (idx & 15) * 4;
        uint2 val = *(const uint2*)&obuf[wv][r][c4];
        int tok = g * TG + t * 16 + r;
        *(uint2*)(xo + ((size_t)(b * TT + tok)) * CC + h * HS + c4) = val;
      }
    } else {
      if (lo == 0) {
#pragma unroll
        for (int m = 0; m < 4; ++m)
#pragma unroll
          for (int r = 0; r < 4; ++r)
            attm[(size_t)blk * 64 + m * 16 + 4 * hi + r] = oac[m][r];
      }
    }
  }
}

// ---------------- second (tiny) causal attention over 15 group-mean tokens ----------------
__global__ __launch_bounds__(64) void attn2(const float* __restrict__ yq,
                                            const float* __restrict__ yk,
                                            const float* __restrict__ attm,
                                            float* __restrict__ yv) {
  __shared__ float qs2[15][64], ks2[15][64], avs[15][64], srow[16];
  int bh = blockIdx.x, lane = threadIdx.x;
  for (int j = 0; j < 15; ++j) {
    qs2[j][lane] = yq[((size_t)bh * 15 + j) * 64 + lane];
    ks2[j][lane] = yk[((size_t)bh * 15 + j) * 64 + lane];
    avs[j][lane] = attm[((size_t)bh * 16 + j) * 64 + lane];
  }
  __syncthreads();
  for (int i = 0; i < 15; ++i) {
    float qv = qs2[i][lane];
    for (int j = 0; j <= i; ++j) {
      float t = qv * ks2[j][lane];
#pragma unroll
      for (int off = 32; off > 0; off >>= 1) t += __shfl_xor(t, off);
      if (lane == 0) srow[j] = t * 0.125f;
    }
    __syncthreads();
    float mx = -INFINITY;
    for (int j = 0; j <= i; ++j) mx = fmaxf(mx, srow[j]);
    float den = 0;
    for (int j = 0; j <= i; ++j) den += __expf(srow[j] - mx);
    float inv = 1.0f / den;
    float o = 0;
    for (int j = 0; j <= i; ++j) o += __expf(srow[j] - mx) * inv * avs[j][lane];
    yv[((size_t)bh * 15 + i) * 64 + lane] = o;
    __syncthreads();
  }
}

extern "C" void kernel_launch(void* const* d_in, const int* in_sizes, int n_in,
                              void* d_out, int out_size, void* d_ws, size_t ws_size,
                              hipStream_t stream) {
  const float* x      = (const float*)d_in[0];
  const float* w_attn = (const float*)d_in[1];
  const float* w_proj = (const float*)d_in[2];
  const float* fc     = (const float*)d_in[3];
  const float* fs     = (const float*)d_in[4];
  float* out = (float*)d_out;

  char* ws = (char*)d_ws;
  ushort* xb   = (ushort*)(ws);               // x bf16; dead after qkv gemm
  ushort* xo   = (ushort*)(ws);               // reuse xb region (attn1 output)
  ushort* wab  = (ushort*)(ws + 16777216);    // dead after qkv gemm
  float*  attm = (float*) (ws + 16777216);    // reuse wab region
  ushort* wpb  = (ushort*)(ws + 23068672);
  ushort* qg   = (ushort*)(ws + 25165824);    // (B,H,G,129,64) bf16
  ushort* kg   = (ushort*)(ws + 42074112);
  ushort* vg   = (ushort*)(ws + 58982400);    // end 75,890,688

  float* yq = out + 8388608;
  float* yk = out + 8450048;
  float* yv = out + 8511488;

  cvt_f32_bf16<<<2048, 256, 0, stream>>>(x, xb, 8388608 / 4);
  cvt_f32_bf16<<<1024, 256, 0, stream>>>(w_attn, wab, 3145728 / 4);
  cvt_f32_bf16<<<512, 256, 0, stream>>>(w_proj, wpb, 1048576 / 4);
  gemm_qkv_rope<<<dim3(24, 64), 256, 0, stream>>>(xb, wab, fc, fs, qg, kg, vg, yq, yk);
  attn1<<<1024, 256, 0, stream>>>(qg, kg, vg, xo, attm);
  attn2<<<64, 64, 0, stream>>>(yq, yk, attm, yv);
  gemm_bt<false><<<dim3(8, 64), 256, 0, stream>>>(xo, wpb, out, 8192, 1024, 1024);
}